// Round 1
// 1303.041 us; speedup vs baseline: 1.0039x; 1.0039x over previous
//
#include <hip/hip_runtime.h>

// InnerProduct: ip[r,p] = sum_f w[p,f]^2 * sum_e x[r,f,e]^2
// x: [32768, 64, 128] fp32 (1 GiB, read once), w: [10, 64] fp32, out: [32768, 10] fp32
// Memory-bound streaming kernel: floor ~170 us @ 6.3 TB/s.
//
// R1 change vs baseline: 4 rows per wave. Weights (3 LDS broadcasts) are fetched
// once per iteration and applied to 4 independent row streams -> 4x less in-loop
// LDS traffic per row, 4x more independent loads in flight per wave. x loads are
// nontemporal (zero reuse, don't pollute L2).

typedef float f4 __attribute__((ext_vector_type(4)));
typedef float f2 __attribute__((ext_vector_type(2)));

#define BATCH   32768
#define NF      64
#define EMBED   128
#define OUT_N   10
#define ROW_F   (NF * EMBED)     // 8192 floats per row
#define ROW_F4  (ROW_F / 4)      // 2048 float4 per row
#define W2_PAD  12               // pad 10 -> 12 floats (48B rows, 16B aligned)
#define RPW     4                // rows per wave
#define RPB     16               // rows per block (4 waves x 4 rows)

__global__ __launch_bounds__(256) void ip_kernel(
    const float* __restrict__ x,
    const float* __restrict__ w,
    float* __restrict__ out)
{
    // Stage squared+transposed weights in LDS: w2[f][p] = w[p][f]^2
    __shared__ float w2[NF * W2_PAD];
    for (int i = threadIdx.x; i < OUT_N * NF; i += 256) {
        int p = i >> 6;        // i / 64
        int f = i & 63;        // i % 64
        float v = w[i];
        w2[f * W2_PAD + p] = v * v;
    }
    __syncthreads();

    const int lane = threadIdx.x & 63;
    const int wid  = threadIdx.x >> 6;
    const int half = lane >> 5;      // 0 for lanes 0..31, 1 for lanes 32..63

    // 4 contiguous rows per wave; 2048 blocks cover BATCH exactly.
    const size_t row0 = (size_t)blockIdx.x * RPB + (size_t)wid * RPW;
    const f4* __restrict__ base = (const f4*)(x + row0 * ROW_F);

    float acc[RPW][OUT_N];
    #pragma unroll
    for (int r = 0; r < RPW; ++r)
        #pragma unroll
        for (int p = 0; p < OUT_N; ++p) acc[r][p] = 0.0f;

    // Each iteration: 4 rows x 64 lanes x float4 = 1 KB/row, covering fields
    // (2t, 2t+1) of each row. Lane's float4 lies in field f = 2t + half.
    #pragma unroll 2
    for (int t = 0; t < 32; ++t) {
        f4 v0 = __builtin_nontemporal_load(&base[0 * ROW_F4 + t * 64 + lane]);
        f4 v1 = __builtin_nontemporal_load(&base[1 * ROW_F4 + t * 64 + lane]);
        f4 v2 = __builtin_nontemporal_load(&base[2 * ROW_F4 + t * 64 + lane]);
        f4 v3 = __builtin_nontemporal_load(&base[3 * ROW_F4 + t * 64 + lane]);

        // One weight fetch serves all 4 rows (half-wave LDS broadcast).
        const float* wrow = &w2[(2 * t + half) * W2_PAD];
        f4 wa = *(const f4*)&wrow[0];   // w2[f][0..3]
        f4 wb = *(const f4*)&wrow[4];   // w2[f][4..7]
        f2 wc = *(const f2*)&wrow[8];   // w2[f][8..9]

        float s0 = v0[0]*v0[0] + v0[1]*v0[1] + v0[2]*v0[2] + v0[3]*v0[3];
        float s1 = v1[0]*v1[0] + v1[1]*v1[1] + v1[2]*v1[2] + v1[3]*v1[3];
        float s2 = v2[0]*v2[0] + v2[1]*v2[1] + v2[2]*v2[2] + v2[3]*v2[3];
        float s3 = v3[0]*v3[0] + v3[1]*v3[1] + v3[2]*v3[2] + v3[3]*v3[3];

        #define APPLY(r, sv)                                    \
            acc[r][0] += (sv) * wa[0]; acc[r][1] += (sv) * wa[1]; \
            acc[r][2] += (sv) * wa[2]; acc[r][3] += (sv) * wa[3]; \
            acc[r][4] += (sv) * wb[0]; acc[r][5] += (sv) * wb[1]; \
            acc[r][6] += (sv) * wb[2]; acc[r][7] += (sv) * wb[3]; \
            acc[r][8] += (sv) * wc[0]; acc[r][9] += (sv) * wc[1];
        APPLY(0, s0)
        APPLY(1, s1)
        APPLY(2, s2)
        APPLY(3, s3)
        #undef APPLY
    }

    // Butterfly reduction across the 64-lane wave (all lanes end with full sums)
    #pragma unroll
    for (int off = 32; off >= 1; off >>= 1) {
        #pragma unroll
        for (int r = 0; r < RPW; ++r)
            #pragma unroll
            for (int p = 0; p < OUT_N; ++p)
                acc[r][p] += __shfl_xor(acc[r][p], off, 64);
    }

    if (lane == 0) {
        #pragma unroll
        for (int r = 0; r < RPW; ++r) {
            float* o = out + (row0 + r) * OUT_N;
            #pragma unroll
            for (int p = 0; p < OUT_N; ++p) o[p] = acc[r][p];
        }
    }
}

extern "C" void kernel_launch(void* const* d_in, const int* in_sizes, int n_in,
                              void* d_out, int out_size, void* d_ws, size_t ws_size,
                              hipStream_t stream) {
    const float* x = (const float*)d_in[0];   // [32768, 64, 128]
    const float* w = (const float*)d_in[1];   // [10, 64]
    float* out = (float*)d_out;               // [32768, 10]

    dim3 grid(BATCH / RPB);   // 2048 blocks, 16 rows each
    dim3 block(256);          // 4 waves x 4 rows/wave
    ip_kernel<<<grid, block, 0, stream>>>(x, w, out);
}